// Round 2
// baseline (802.821 us; speedup 1.0000x reference)
//
#include <hip/hip_runtime.h>

#define T_TOK 4096
#define DDIM  2048
#define NEXP  8
#define HDIM  1024
#define HSDIM 2048
#define NASSIGN 8192   // T_TOK * TOP_K
#define MAXTILES 72    // sum ceil(n_e/128) <= 8192/128 + 8

typedef __attribute__((ext_vector_type(8))) short bf16x8;
typedef __attribute__((ext_vector_type(4))) float f32x4;

__device__ __forceinline__ ushort f2bf(float f) {
  union { float f; unsigned u; } v; v.f = f;
  unsigned r = v.u + 0x7FFFu + ((v.u >> 16) & 1u);
  return (ushort)(r >> 16);
}

__device__ __forceinline__ void gload16(const void* g, void* s) {
  __builtin_amdgcn_global_load_lds((const __attribute__((address_space(1))) void*)g,
                                   (__attribute__((address_space(3))) void*)s, 16, 0, 0);
}

// ---------------- control block layout (ints) ----------------
// [0] ntiles | [8..15] cnt | [16..23] cursor | [24..32] off
// [64..143] tile_expert | [160..239] tile_row0 | [256..335] tile_end

__global__ void zero_k(int* ctl) {
  int i = threadIdx.x;
#pragma unroll
  for (int j = 0; j < 4; ++j) ctl[i + j * 256] = 0;
}

// one wave per token: logits, softmax-top2 renorm, counts
__global__ void router_k(const float* __restrict__ x, const float* __restrict__ rw,
                         int* __restrict__ ctl, int* __restrict__ tidx,
                         float* __restrict__ twt) {
  int t = blockIdx.x;
  int lane = threadIdx.x;
  const float* xr = x + (size_t)t * DDIM;
  float acc[NEXP];
#pragma unroll
  for (int e = 0; e < NEXP; ++e) acc[e] = 0.f;
  for (int d0 = lane * 4; d0 < DDIM; d0 += 256) {
    float4 xv = *(const float4*)(xr + d0);
    const float* rwp = rw + (size_t)d0 * NEXP;
#pragma unroll
    for (int e = 0; e < NEXP; ++e)
      acc[e] += xv.x * rwp[e] + xv.y * rwp[NEXP + e] +
                xv.z * rwp[2 * NEXP + e] + xv.w * rwp[3 * NEXP + e];
  }
#pragma unroll
  for (int e = 0; e < NEXP; ++e) {
#pragma unroll
    for (int off = 32; off >= 1; off >>= 1) acc[e] += __shfl_xor(acc[e], off, 64);
  }
  if (lane == 0) {
    int i0 = 0; float m0 = acc[0];
#pragma unroll
    for (int e = 1; e < NEXP; ++e) if (acc[e] > m0) { m0 = acc[e]; i0 = e; }
    int i1 = -1; float m1 = -3.4e38f;
#pragma unroll
    for (int e = 0; e < NEXP; ++e) if (e != i0 && acc[e] > m1) { m1 = acc[e]; i1 = e; }
    float w0 = 1.f / (1.f + __expf(m1 - m0));  // softmax over top-2 == renormalized top-2 probs
    float w1 = 1.f - w0;
    tidx[2 * t] = i0;     twt[2 * t] = w0;
    tidx[2 * t + 1] = i1; twt[2 * t + 1] = w1;
    atomicAdd(&ctl[8 + i0], 1);
    atomicAdd(&ctl[8 + i1], 1);
  }
}

__global__ void plan_k(int* ctl) {
  if (threadIdx.x != 0 || blockIdx.x != 0) return;
  int off = 0, nt = 0;
  for (int e = 0; e < NEXP; ++e) {
    int c = ctl[8 + e];
    ctl[24 + e] = off;
    ctl[16 + e] = off;  // cursor starts at segment base
    int ntile = (c + 127) >> 7;
    for (int j = 0; j < ntile; ++j) {
      ctl[64 + nt] = e;
      ctl[160 + nt] = off + j * 128;
      ctl[256 + nt] = off + c;
      ++nt;
    }
    off += c;
  }
  ctl[24 + NEXP] = off;
  ctl[0] = nt;
}

__global__ void scatter_k(const int* __restrict__ tidx, const float* __restrict__ twt,
                          int* __restrict__ ctl, int* __restrict__ stok,
                          float* __restrict__ swt) {
  int t = blockIdx.x * blockDim.x + threadIdx.x;
  if (t >= T_TOK) return;
#pragma unroll
  for (int k = 0; k < 2; ++k) {
    int e = tidx[2 * t + k];
    int p = atomicAdd(&ctl[16 + e], 1);
    stok[p] = t;
    swt[p] = twt[2 * t + k];
  }
}

// f32 -> bf16 elementwise (8/thread)
__global__ void cvt_k(const float* __restrict__ in, ushort* __restrict__ out) {
  long long i = ((long long)blockIdx.x * blockDim.x + threadIdx.x) * 8;
  float4 a = *(const float4*)(in + i);
  float4 b = *(const float4*)(in + i + 4);
  ushort4 o0 = { f2bf(a.x), f2bf(a.y), f2bf(a.z), f2bf(a.w) };
  ushort4 o1 = { f2bf(b.x), f2bf(b.y), f2bf(b.z), f2bf(b.w) };
  *(ushort4*)(out + i) = o0;
  *(ushort4*)(out + i + 4) = o1;
}

// [R][C] f32 -> [C][R] bf16 transpose+convert, 64x64 LDS tiles, slice = blockIdx.z
__global__ void tcvt_k(const float* __restrict__ in, ushort* __restrict__ out,
                       int R, int C) {
  __shared__ float tile[64][65];
  in  += (size_t)blockIdx.z * R * C;
  out += (size_t)blockIdx.z * R * C;
  int c0 = blockIdx.x * 64, r0 = blockIdx.y * 64;
  int tx = threadIdx.x & 15, ty = threadIdx.x >> 4;
#pragma unroll
  for (int i = 0; i < 4; ++i) {
    float4 v = *(const float4*)(in + (size_t)(r0 + ty + 16 * i) * C + c0 + tx * 4);
    tile[ty + 16 * i][tx * 4 + 0] = v.x;
    tile[ty + 16 * i][tx * 4 + 1] = v.y;
    tile[ty + 16 * i][tx * 4 + 2] = v.z;
    tile[ty + 16 * i][tx * 4 + 3] = v.w;
  }
  __syncthreads();
#pragma unroll
  for (int i = 0; i < 4; ++i) {
    ushort4 o = { f2bf(tile[tx * 4 + 0][ty + 16 * i]),
                  f2bf(tile[tx * 4 + 1][ty + 16 * i]),
                  f2bf(tile[tx * 4 + 2][ty + 16 * i]),
                  f2bf(tile[tx * 4 + 3][ty + 16 * i]) };
    *(ushort4*)(out + (size_t)(c0 + ty + 16 * i) * R + r0 + tx * 4) = o;
  }
}

// ---------------- fused gate+up GEMM (SwiGLU front) ----------------
// A: x_bf [*, 2048] (rows gathered via token list for ROUTED)
// BgT/BuT: [n][k] bf16 (k = D = 2048 contiguous); N = HDIM or HSDIM
// Hout bf16 [rows][N] = silu(A@Bg) * (A@Bu)
template <bool ROUTED>
__global__ __launch_bounds__(256, 2) void gateup_k(
    const ushort* __restrict__ Ax, const ushort* __restrict__ BgT,
    const ushort* __restrict__ BuT, ushort* __restrict__ Hout,
    const int* __restrict__ ctl, const int* __restrict__ stok, int N) {
  __shared__ ushort As[128 * 32];
  __shared__ ushort Bgs[128 * 32];
  __shared__ ushort Bus[128 * 32];
  __shared__ int toks[128];

  int tid = threadIdx.x;
  int row0, nrows;
  const ushort *Bg, *Bu;
  if (ROUTED) {
    if (blockIdx.x >= ctl[0]) return;
    row0 = ctl[160 + blockIdx.x];
    int end = ctl[256 + blockIdx.x];
    nrows = end - row0; if (nrows > 128) nrows = 128;
    size_t es = (size_t)ctl[64 + blockIdx.x] * HDIM * DDIM;
    Bg = BgT + es; Bu = BuT + es;
    if (tid < 128) toks[tid] = (tid < nrows) ? stok[row0 + tid] : 0;
  } else {
    row0 = blockIdx.x * 128; nrows = 128;
    Bg = BgT; Bu = BuT;
    if (tid < 128) toks[tid] = row0 + tid;
  }
  int col0 = blockIdx.y * 128;
  __syncthreads();

  int srow = tid >> 2, skc = tid & 3;
  const ushort* aS0 = Ax + (size_t)toks[srow] * DDIM + skc * 8;
  const ushort* aS1 = Ax + (size_t)toks[64 + srow] * DDIM + skc * 8;
  const ushort* bgS0 = Bg + (size_t)(col0 + srow) * DDIM + skc * 8;
  const ushort* bgS1 = Bg + (size_t)(col0 + 64 + srow) * DDIM + skc * 8;
  const ushort* buS0 = Bu + (size_t)(col0 + srow) * DDIM + skc * 8;
  const ushort* buS1 = Bu + (size_t)(col0 + 64 + srow) * DDIM + skc * 8;
  ushort* aD0 = As + tid * 8;   ushort* aD1 = As + (256 + tid) * 8;
  ushort* bgD0 = Bgs + tid * 8; ushort* bgD1 = Bgs + (256 + tid) * 8;
  ushort* buD0 = Bus + tid * 8; ushort* buD1 = Bus + (256 + tid) * 8;

  int lane = tid & 63, w = tid >> 6;
  int g = lane >> 4, r16 = lane & 15;
  int wr = (w >> 1) * 64, wc = (w & 1) * 64;

  f32x4 accg[4][4], accu[4][4];
  f32x4 z = {0.f, 0.f, 0.f, 0.f};
#pragma unroll
  for (int i = 0; i < 4; ++i)
#pragma unroll
    for (int j = 0; j < 4; ++j) { accg[i][j] = z; accu[i][j] = z; }

  for (int k0 = 0; k0 < DDIM; k0 += 32) {
    gload16(aS0 + k0, aD0);   gload16(aS1 + k0, aD1);
    gload16(bgS0 + k0, bgD0); gload16(bgS1 + k0, bgD1);
    gload16(buS0 + k0, buD0); gload16(buS1 + k0, buD1);
    __syncthreads();
    bf16x8 af[4], bgf[4], buf_[4];
#pragma unroll
    for (int mf = 0; mf < 4; ++mf)
      af[mf] = *(const bf16x8*)(As + (wr + mf * 16 + r16) * 32 + g * 8);
#pragma unroll
    for (int nf = 0; nf < 4; ++nf) {
      bgf[nf] = *(const bf16x8*)(Bgs + (wc + nf * 16 + r16) * 32 + g * 8);
      buf_[nf] = *(const bf16x8*)(Bus + (wc + nf * 16 + r16) * 32 + g * 8);
    }
#pragma unroll
    for (int mf = 0; mf < 4; ++mf)
#pragma unroll
      for (int nf = 0; nf < 4; ++nf) {
        accg[mf][nf] = __builtin_amdgcn_mfma_f32_16x16x32_bf16(af[mf], bgf[nf], accg[mf][nf], 0, 0, 0);
        accu[mf][nf] = __builtin_amdgcn_mfma_f32_16x16x32_bf16(af[mf], buf_[nf], accu[mf][nf], 0, 0, 0);
      }
    __syncthreads();
  }

#pragma unroll
  for (int mf = 0; mf < 4; ++mf) {
#pragma unroll
    for (int j = 0; j < 4; ++j) {
      int rloc = wr + mf * 16 + g * 4 + j;  // D row = (lane>>4)*4 + reg (m89-verified)
      if (rloc < nrows) {
        // col = col0 + wc + nf*16 + (lane&15)   [R1 fix: wc was missing]
        size_t obase = (size_t)(row0 + rloc) * N + col0 + wc;
#pragma unroll
        for (int nf = 0; nf < 4; ++nf) {
          float gv = accg[mf][nf][j];
          float uv = accu[mf][nf][j];
          float hv = gv / (1.f + __expf(-gv)) * uv;
          Hout[obase + nf * 16 + r16] = f2bf(hv);
        }
      }
    }
  }
}

// ---------------- down-proj GEMM ----------------
// A: bf16 [rows][Ktot]; BdT: [n=d][k] bf16; ROUTED: atomicAdd(out[tok], wt*acc),
// shared: plain store (must run before routed).
template <bool ROUTED>
__global__ __launch_bounds__(256, 2) void down_k(
    const ushort* __restrict__ Ah, const ushort* __restrict__ BdT,
    float* __restrict__ Out, const int* __restrict__ ctl,
    const int* __restrict__ stok, const float* __restrict__ swt, int Ktot) {
  __shared__ ushort As[128 * 32];
  __shared__ ushort Bs[128 * 32];
  __shared__ int tokl[128];
  __shared__ float wtl[128];

  int tid = threadIdx.x;
  int row0, nrows;
  const ushort* Bd;
  if (ROUTED) {
    if (blockIdx.x >= ctl[0]) return;
    row0 = ctl[160 + blockIdx.x];
    int end = ctl[256 + blockIdx.x];
    nrows = end - row0; if (nrows > 128) nrows = 128;
    Bd = BdT + (size_t)ctl[64 + blockIdx.x] * DDIM * HDIM;
    if (tid < 128) {
      bool v = tid < nrows;
      tokl[tid] = v ? stok[row0 + tid] : 0;
      wtl[tid] = v ? swt[row0 + tid] : 0.f;
    }
  } else {
    row0 = blockIdx.x * 128; nrows = 128;
    Bd = BdT;
  }
  int col0 = blockIdx.y * 128;
  __syncthreads();

  int srow = tid >> 2, skc = tid & 3;
  const ushort* aS0 = Ah + (size_t)(row0 + srow) * Ktot + skc * 8;
  const ushort* aS1 = Ah + (size_t)(row0 + 64 + srow) * Ktot + skc * 8;
  const ushort* bS0 = Bd + (size_t)(col0 + srow) * Ktot + skc * 8;
  const ushort* bS1 = Bd + (size_t)(col0 + 64 + srow) * Ktot + skc * 8;
  ushort* aD0 = As + tid * 8; ushort* aD1 = As + (256 + tid) * 8;
  ushort* bD0 = Bs + tid * 8; ushort* bD1 = Bs + (256 + tid) * 8;

  int lane = tid & 63, w = tid >> 6;
  int g = lane >> 4, r16 = lane & 15;
  int wr = (w >> 1) * 64, wc = (w & 1) * 64;

  f32x4 acc[4][4];
  f32x4 z = {0.f, 0.f, 0.f, 0.f};
#pragma unroll
  for (int i = 0; i < 4; ++i)
#pragma unroll
    for (int j = 0; j < 4; ++j) acc[i][j] = z;

  for (int k0 = 0; k0 < Ktot; k0 += 32) {
    gload16(aS0 + k0, aD0); gload16(aS1 + k0, aD1);
    gload16(bS0 + k0, bD0); gload16(bS1 + k0, bD1);
    __syncthreads();
    bf16x8 af[4], bf[4];
#pragma unroll
    for (int mf = 0; mf < 4; ++mf)
      af[mf] = *(const bf16x8*)(As + (wr + mf * 16 + r16) * 32 + g * 8);
#pragma unroll
    for (int nf = 0; nf < 4; ++nf)
      bf[nf] = *(const bf16x8*)(Bs + (wc + nf * 16 + r16) * 32 + g * 8);
#pragma unroll
    for (int mf = 0; mf < 4; ++mf)
#pragma unroll
      for (int nf = 0; nf < 4; ++nf)
        acc[mf][nf] = __builtin_amdgcn_mfma_f32_16x16x32_bf16(af[mf], bf[nf], acc[mf][nf], 0, 0, 0);
    __syncthreads();
  }

#pragma unroll
  for (int mf = 0; mf < 4; ++mf) {
#pragma unroll
    for (int j = 0; j < 4; ++j) {
      int rloc = wr + mf * 16 + g * 4 + j;
      if (rloc < nrows) {
        if (ROUTED) {
          int t = tokl[rloc];
          float wt = wtl[rloc];
          // col = col0 + wc + nf*16 + (lane&15)   [R1 fix: wc was missing]
          size_t obase = (size_t)t * DDIM + col0 + wc;
#pragma unroll
          for (int nf = 0; nf < 4; ++nf)
            atomicAdd(&Out[obase + nf * 16 + r16], wt * acc[mf][nf][j]);
        } else {
          size_t obase = (size_t)(row0 + rloc) * DDIM + col0 + wc;  // [R1 fix]
#pragma unroll
          for (int nf = 0; nf < 4; ++nf)
            Out[obase + nf * 16 + r16] = acc[mf][nf][j];
        }
      }
    }
  }
}

extern "C" void kernel_launch(void* const* d_in, const int* in_sizes, int n_in,
                              void* d_out, int out_size, void* d_ws, size_t ws_size,
                              hipStream_t stream) {
  const float* x   = (const float*)d_in[0];
  const float* rw  = (const float*)d_in[1];
  const float* wg  = (const float*)d_in[2];
  const float* wu  = (const float*)d_in[3];
  const float* wd  = (const float*)d_in[4];
  const float* swg = (const float*)d_in[5];
  const float* swu = (const float*)d_in[6];
  const float* swd = (const float*)d_in[7];
  float* out = (float*)d_out;

  char* ws = (char*)d_ws;
  size_t off = 0;
  auto alloc = [&](size_t bytes) {
    char* p = ws + off;
    off += (bytes + 4095) & ~(size_t)4095;
    return p;
  };
  int*    ctl   = (int*)alloc(4096);
  int*    tidx  = (int*)alloc(NASSIGN * 4);
  float*  twt   = (float*)alloc(NASSIGN * 4);
  int*    stok  = (int*)alloc(NASSIGN * 4);
  float*  swt_  = (float*)alloc(NASSIGN * 4);
  ushort* xbf   = (ushort*)alloc((size_t)T_TOK * DDIM * 2);
  ushort* wgT   = (ushort*)alloc((size_t)NEXP * HDIM * DDIM * 2);
  ushort* wuT   = (ushort*)alloc((size_t)NEXP * HDIM * DDIM * 2);
  ushort* wdT   = (ushort*)alloc((size_t)NEXP * DDIM * HDIM * 2);
  ushort* swgT  = (ushort*)alloc((size_t)HSDIM * DDIM * 2);
  ushort* swuT  = (ushort*)alloc((size_t)HSDIM * DDIM * 2);
  ushort* swdT  = (ushort*)alloc((size_t)DDIM * HSDIM * 2);
  ushort* hbuf  = (ushort*)alloc((size_t)NASSIGN * HDIM * 2);
  ushort* shbuf = (ushort*)alloc((size_t)T_TOK * HSDIM * 2);
  if (off > ws_size) return;  // workspace too small — bail (will show as absmax fail, not crash)

  // routing chain
  zero_k<<<1, 256, 0, stream>>>(ctl);
  router_k<<<T_TOK, 64, 0, stream>>>(x, rw, ctl, tidx, twt);
  plan_k<<<1, 64, 0, stream>>>(ctl);
  scatter_k<<<16, 256, 0, stream>>>(tidx, twt, ctl, stok, swt_);

  // precision/layout prepasses
  cvt_k<<<(T_TOK * DDIM / 8) / 256, 256, 0, stream>>>(x, xbf);
  tcvt_k<<<dim3(HDIM / 64, DDIM / 64, NEXP), 256, 0, stream>>>(wg, wgT, DDIM, HDIM);
  tcvt_k<<<dim3(HDIM / 64, DDIM / 64, NEXP), 256, 0, stream>>>(wu, wuT, DDIM, HDIM);
  tcvt_k<<<dim3(DDIM / 64, HDIM / 64, NEXP), 256, 0, stream>>>(wd, wdT, HDIM, DDIM);
  tcvt_k<<<dim3(HSDIM / 64, DDIM / 64, 1), 256, 0, stream>>>(swg, swgT, DDIM, HSDIM);
  tcvt_k<<<dim3(HSDIM / 64, DDIM / 64, 1), 256, 0, stream>>>(swu, swuT, DDIM, HSDIM);
  tcvt_k<<<dim3(DDIM / 64, HSDIM / 64, 1), 256, 0, stream>>>(swd, swdT, HSDIM, DDIM);

  // GEMMs: shared-down writes all of out first; routed-down atomically adds on top
  gateup_k<true><<<dim3(MAXTILES, HDIM / 128), 256, 0, stream>>>(xbf, wgT, wuT, hbuf, ctl, stok, HDIM);
  gateup_k<false><<<dim3(T_TOK / 128, HSDIM / 128), 256, 0, stream>>>(xbf, swgT, swuT, shbuf, ctl, stok, HSDIM);
  down_k<false><<<dim3(T_TOK / 128, DDIM / 128), 256, 0, stream>>>(shbuf, swdT, out, ctl, stok, swt_, HSDIM);
  down_k<true><<<dim3(MAXTILES, DDIM / 128), 256, 0, stream>>>(hbuf, wdT, out, ctl, stok, swt_, HDIM);
}